// Round 11
// baseline (149.356 us; speedup 1.0000x reference)
//
#include <hip/hip_runtime.h>

// VQ-VAE quantizer: h (256,512,32) fp32, embeddings (1024,32) fp32.
// d_out (fp32): quantized_st [4194304] | indices [131072] | loss [131072]
//
// R11: R9's fused certified-filter scan with the b-table staged in LDS
// (64 KB static; the 64KB table thrashed the 32KB L1 -> all waves stalled on
// L2, which neither R9's 4 nor R10's 8 waves/SIMD could hide). Candidate
// lists live in OWNER-LANE REGISTERS (packed u64, 10 bits/cand, cap 6),
// decoded from the sweep2 qualify-ballots -> LDS holds ONLY the table.
// Full 1024-candidate scan per wave (restores the n==1 ~82% fast path that
// R10's per-half thresholds destroyed).
//   prep:  e2 (numpy pairwise) + bf16 B-frag table (MFMA lane layout)
//   scan:  block stages bfrag->LDS; per wave (32 rows): sweep1 approx min/row
//          (MFMA), T_row = 2^-16*Sum|f_k| + 1e-4; sweep2 recompute
//          (bit-identical), ballot-decode qualifiers into packed regs;
//          tail: overflow rows (P~1e-6) -> wave-cooperative exact scan;
//          owner lane: n==1 -> done, else bit-exact numpy recheck (pairwise
//          ||f||^2, sequential fmaf dot, fl(fl(f2+e2)-2dot), u64 key
//          enc(d)<<32|c = first-occurrence argmin); epilogue.
// History: R3 270 -> R4 240 -> R5 193 -> R6 871 -> R7 566 -> R8 141 ->
//          R9 131 (scan 72) -> R10 132 (scan 76; TLP-doubling neutral:
//          common stall is the L1-thrashing b-table, not wave count).

#define EMB_N 1024
#define DIM 32
#define NVEC (256 * 512)
#define NTILES (EMB_N / 16)
#define MAXC 6

typedef unsigned long long u64;
typedef unsigned int u32;
typedef unsigned short ushortT;
typedef __attribute__((ext_vector_type(8))) short bf16x8;
typedef __attribute__((ext_vector_type(4))) float f32x4;

__device__ __forceinline__ u32 enc_f32(float x) {
    u32 u = __float_as_uint(x);
    return (u & 0x80000000u) ? ~u : (u | 0x80000000u);  // monotone order-preserving
}
__device__ __forceinline__ ushortT f2bf(float f) {  // RNE fp32->bf16
    u32 u = __float_as_uint(f);
    return (ushortT)((u + 0x7FFFu + ((u >> 16) & 1u)) >> 16);
}
__device__ __forceinline__ u64 shflx_u64(u64 x, int m) {
    int lo = __shfl_xor((int)(u32)x, m);
    int hi = __shfl_xor((int)(x >> 32), m);
    return ((u64)(u32)hi << 32) | (u32)lo;
}

// numpy pairwise ||x||^2, n=32: 8 accumulators stride 8, fixed combine tree
__device__ __forceinline__ float norm2_np(const float* fr) {
    float sq[DIM];
#pragma unroll
    for (int i = 0; i < DIM; ++i) sq[i] = fr[i] * fr[i];
    float r[8];
#pragma unroll
    for (int j = 0; j < 8; ++j)
        r[j] = ((sq[j] + sq[j + 8]) + sq[j + 16]) + sq[j + 24];
    return ((r[0] + r[1]) + (r[2] + r[3])) + ((r[4] + r[5]) + (r[6] + r[7]));
}

// ---- prep: e2 + bf16 B-frag table. frag(nt,lane,j) = bf16(emb[nt*16+(lane&15)][(lane>>4)*8+j])
__global__ __launch_bounds__(256) void prep_kernel(
    const float* __restrict__ emb, float* __restrict__ e2,
    ushortT* __restrict__ bfrag)
{
#pragma clang fp contract(off)
    const int t = blockIdx.x * 256 + threadIdx.x;    // 0..4095
    const int l = t & 63;
    const int row = ((t >> 6) << 4) + (l & 15);
    const int k0 = (l >> 4) * 8;
    const float* ep = emb + (size_t)row * DIM + k0;
    ushortT* dst = bfrag + (size_t)t * 8;
#pragma unroll
    for (int j = 0; j < 8; ++j) dst[j] = f2bf(ep[j]);
    if (t < EMB_N) {
        const float* e = emb + (size_t)t * DIM;
        float tmp[DIM];
#pragma unroll
        for (int i = 0; i < DIM; ++i) tmp[i] = e[i];
        e2[t] = norm2_np(tmp);
    }
}

// ---- fused scan: LDS-staged table, 1 wave = 32 rows, register cand lists ----
__global__ __launch_bounds__(256) void vq_scan(
    const float* __restrict__ h,
    const float* __restrict__ emb,
    const float* __restrict__ e2,
    const ushortT* __restrict__ bfrag,
    float* __restrict__ out_q, float* __restrict__ out_idx,
    float* __restrict__ out_loss)
{
#pragma clang fp contract(off)
    __shared__ __align__(16) ushortT s_b[EMB_N * DIM];   // exactly 64 KB

    // cooperative fill: 65536 B = 4096 x uint4, 256 threads x 16 iters
    {
        const uint4* src = (const uint4*)bfrag;
        uint4* dst = (uint4*)s_b;
#pragma unroll 4
        for (int o = threadIdx.x; o < 4096; o += 256) dst[o] = src[o];
    }

    const int wid   = (blockIdx.x * 256 + threadIdx.x) >> 6;  // 0..4095
    const int lane  = threadIdx.x & 63;
    const int col16 = lane & 15;
    const int quad  = lane >> 4;
    const size_t row0 = (size_t)wid * 32;

    // A-frags for rows row0+col16 (tile0), row0+16+col16 (tile1); fp32 abs-sums
    bf16x8 afr0, afr1;
    float sa0, sa1;
    {
        const float* ap = h + (row0 + col16) * DIM + quad * 8;
        float4 x = *(const float4*)ap, y = *(const float4*)(ap + 4);
        afr0[0]=(short)f2bf(x.x); afr0[1]=(short)f2bf(x.y); afr0[2]=(short)f2bf(x.z); afr0[3]=(short)f2bf(x.w);
        afr0[4]=(short)f2bf(y.x); afr0[5]=(short)f2bf(y.y); afr0[6]=(short)f2bf(y.z); afr0[7]=(short)f2bf(y.w);
        sa0 = fabsf(x.x)+fabsf(x.y)+fabsf(x.z)+fabsf(x.w)+fabsf(y.x)+fabsf(y.y)+fabsf(y.z)+fabsf(y.w);
        const float* bp = ap + 16 * DIM;
        float4 u = *(const float4*)bp, v = *(const float4*)(bp + 4);
        afr1[0]=(short)f2bf(u.x); afr1[1]=(short)f2bf(u.y); afr1[2]=(short)f2bf(u.z); afr1[3]=(short)f2bf(u.w);
        afr1[4]=(short)f2bf(v.x); afr1[5]=(short)f2bf(v.y); afr1[6]=(short)f2bf(v.z); afr1[7]=(short)f2bf(v.w);
        sa1 = fabsf(u.x)+fabsf(u.y)+fabsf(u.z)+fabsf(u.w)+fabsf(v.x)+fabsf(v.y)+fabsf(v.z)+fabsf(v.w);
    }
    sa0 += __shfl_xor(sa0, 16); sa0 += __shfl_xor(sa0, 32);
    sa1 += __shfl_xor(sa1, 16); sa1 += __shfl_xor(sa1, 32);

    __syncthreads();   // table staged

    const f32x4 zacc = {0.f, 0.f, 0.f, 0.f};

    // ---- sweep 1: approx min per slot (slot i: tile i>>2, reg i&3) ----
    float bs[8];
#pragma unroll
    for (int i = 0; i < 8; ++i) bs[i] = 3.4e38f;
#pragma unroll 2
    for (int nt = 0; nt < NTILES; ++nt) {
        bf16x8 b = *(const bf16x8*)(s_b + nt * 512 + lane * 8);
        f32x4 d0 = __builtin_amdgcn_mfma_f32_16x16x32_bf16(afr0, b, zacc, 0, 0, 0);
        f32x4 d1 = __builtin_amdgcn_mfma_f32_16x16x32_bf16(afr1, b, zacc, 0, 0, 0);
        float e2c = e2[nt * 16 + col16];
#pragma unroll
        for (int r = 0; r < 4; ++r) {
            bs[r]     = fminf(bs[r],     __builtin_fmaf(-2.f, d0[r], e2c));
            bs[4 + r] = fminf(bs[4 + r], __builtin_fmaf(-2.f, d1[r], e2c));
        }
    }
#pragma unroll
    for (int m = 1; m < 16; m <<= 1)
#pragma unroll
        for (int i = 0; i < 8; ++i) bs[i] = fminf(bs[i], __shfl_xor(bs[i], m));

    // per-row certified threshold: thr = min + 2^-16*Sum|f| + 1e-4
    float thr[8];
#pragma unroll
    for (int i = 0; i < 8; ++i) {
        float sar = __shfl((i >> 2) ? sa1 : sa0, quad * 4 + (i & 3));
        thr[i] = bs[i] + __builtin_fmaf(sar, 0x1p-16f, 1.0e-4f);
    }

    // ---- sweep 2: recompute (bit-identical), ballot-decode into registers ----
    // owner lane r(<32) collects candidates for row row0+r: from ballot of slot
    // i_r = ((r>>4)<<2)|(r&3), 16-bit field g_r = (r>>2)&3; bit b -> c = nt*16+b.
    u64 packed = 0;      // up to 6 candidates, 10 bits each
    u32 nreal  = 0;      // true qualifier count
    const int i_r = ((lane >> 4) << 2) | (lane & 3);
    const int g_sh = ((lane >> 2) & 3) * 16;
#pragma unroll 2
    for (int nt = 0; nt < NTILES; ++nt) {
        bf16x8 b = *(const bf16x8*)(s_b + nt * 512 + lane * 8);
        f32x4 d0 = __builtin_amdgcn_mfma_f32_16x16x32_bf16(afr0, b, zacc, 0, 0, 0);
        f32x4 d1 = __builtin_amdgcn_mfma_f32_16x16x32_bf16(afr1, b, zacc, 0, 0, 0);
        float e2c = e2[nt * 16 + col16];
        bool q[8];
        bool any = false;
#pragma unroll
        for (int i = 0; i < 8; ++i) {
            float s = __builtin_fmaf(-2.f, ((i >> 2) ? d1[i & 3] : d0[i & 3]), e2c);
            q[i] = (s <= thr[i]);
            any |= q[i];
        }
        if (__any(any)) {
            u64 B0 = __ballot(q[0]), B1 = __ballot(q[1]);
            u64 B2 = __ballot(q[2]), B3 = __ballot(q[3]);
            u64 B4 = __ballot(q[4]), B5 = __ballot(q[5]);
            u64 B6 = __ballot(q[6]), B7 = __ballot(q[7]);
            if (lane < 32) {
                u64 s01 = (i_r & 1) ? B1 : B0;
                u64 s23 = (i_r & 1) ? B3 : B2;
                u64 s45 = (i_r & 1) ? B5 : B4;
                u64 s67 = (i_r & 1) ? B7 : B6;
                u64 t0  = (i_r & 2) ? s23 : s01;
                u64 t1  = (i_r & 2) ? s67 : s45;
                u64 sel = (i_r & 4) ? t1 : t0;
                u32 fld = (u32)(sel >> g_sh) & 0xFFFFu;
                while (fld) {
                    int bit = __ffs(fld) - 1;
                    fld &= fld - 1;
                    u32 c = (u32)(nt * 16 + bit);
                    if (nreal < MAXC) packed |= (u64)c << (nreal * 10);
                    ++nreal;
                }
            }
        }
    }

    // ---- tail A: overflowed rows (P~1e-6) -> wave-cooperative exact scan ----
    int myBidx = -1;
    u64 ovf = __ballot((lane < 32) && (nreal > MAXC));
    while (ovf) {
        const int r = (int)(__ffsll((unsigned long long)ovf) - 1);
        ovf &= ovf - 1;
        const float* fp = h + (row0 + r) * DIM;   // wave-uniform row
        float fu[DIM];
#pragma unroll
        for (int i = 0; i < DIM; i += 4) {
            float4 x = *(const float4*)(fp + i);
            fu[i] = x.x; fu[i + 1] = x.y; fu[i + 2] = x.z; fu[i + 3] = x.w;
        }
        const float f2 = norm2_np(fu);
        u64 bk = ~0ull;
        for (int c = lane; c < EMB_N; c += 64) {
            const float* ep = emb + (size_t)c * DIM;
            float a = 0.f;
#pragma unroll
            for (int k = 0; k < DIM; ++k) a = __builtin_fmaf(fu[k], ep[k], a);
            float dd = (f2 + e2[c]) - (2.0f * a);
            u64 key = ((u64)enc_f32(dd) << 32) | (u32)c;
            if (key < bk) bk = key;
        }
#pragma unroll
        for (int m = 1; m < 64; m <<= 1) {
            u64 o = shflx_u64(bk, m);
            if (o < bk) bk = o;
        }
        if (lane == r) myBidx = (int)(bk & 0xFFFFFFFFu);
    }

    // ---- tail B: owner lane per row -> recheck + epilogue ----
    if (lane < 32) {
        const int row = (int)row0 + lane;
        const float* f = h + (size_t)row * DIM;
        float fr[DIM];
#pragma unroll
        for (int i = 0; i < DIM; i += 4) {
            float4 x = *(const float4*)(f + i);
            fr[i] = x.x; fr[i + 1] = x.y; fr[i + 2] = x.z; fr[i + 3] = x.w;
        }
        int bidx;
        if (myBidx >= 0) {
            bidx = myBidx;
        } else if (nreal == 1) {
            bidx = (int)(packed & 1023u);         // sole certified qualifier
        } else {
            const float f2 = norm2_np(fr);
            u64 best = ~0ull;
            for (u32 j = 0; j < nreal; ++j) {     // nreal <= MAXC here
                const u32 c = (u32)((packed >> (j * 10)) & 1023u);
                const float* ep = emb + (size_t)c * DIM;
                float a = 0.f;
#pragma unroll
                for (int k = 0; k < DIM; ++k) a = __builtin_fmaf(fr[k], ep[k], a);  // BLAS chain
                float dd = (f2 + e2[c]) - (2.0f * a);     // exact numpy formula
                u64 key = ((u64)enc_f32(dd) << 32) | c;
                if (key < best) best = key;
            }
            bidx = (int)(best & 0xFFFFFFFFu);
        }

        const float* qv = emb + (size_t)bidx * DIM;
        float ps = 0.f;
#pragma unroll
        for (int i = 0; i < DIM; i += 4) {
            float4 qx; qx.x = qv[i]; qx.y = qv[i+1]; qx.z = qv[i+2]; qx.w = qv[i+3];
            float dx = qx.x - fr[i], dy = qx.y - fr[i+1], dz = qx.z - fr[i+2], dw = qx.w - fr[i+3];
            ps += dx * dx; ps += dy * dy; ps += dz * dz; ps += dw * dw;
            float4 o;
            o.x = fr[i]     + (qx.x - fr[i]);
            o.y = fr[i + 1] + (qx.y - fr[i + 1]);
            o.z = fr[i + 2] + (qx.z - fr[i + 2]);
            o.w = fr[i + 3] + (qx.w - fr[i + 3]);
            *(float4*)(out_q + (size_t)row * DIM + i) = o;
        }
        float m = ps * (1.0f / DIM);
        out_idx[row]  = (float)bidx;
        out_loss[row] = m * 0.1f + m * 0.1f;
    }
}

// ---------- fallback (R3-style) if workspace too small ----------
__global__ void e2_kernel(const float* __restrict__ emb, float* __restrict__ e2) {
#pragma clang fp contract(off)
    int c = blockIdx.x * blockDim.x + threadIdx.x;
    if (c >= EMB_N) return;
    const float* e = emb + (size_t)c * DIM;
    float tmp[DIM];
#pragma unroll
    for (int i = 0; i < DIM; ++i) tmp[i] = e[i];
    e2[c] = norm2_np(tmp);
}

__global__ __launch_bounds__(256) void vq_kernel(
    const float* __restrict__ h, const float* __restrict__ emb,
    const float* __restrict__ e2, float* __restrict__ out_q,
    float* __restrict__ out_idx, float* __restrict__ out_loss)
{
#pragma clang fp contract(off)
    const int v = blockIdx.x * blockDim.x + threadIdx.x;
    const float* f = h + (size_t)v * DIM;
    float fr[DIM];
#pragma unroll
    for (int i = 0; i < DIM; i += 4) {
        float4 x = *(const float4*)(f + i);
        fr[i] = x.x; fr[i + 1] = x.y; fr[i + 2] = x.z; fr[i + 3] = x.w;
    }
    const float f2 = norm2_np(fr);
    float best = 3.4e38f; int bidx = 0;
#pragma unroll 1
    for (int c = 0; c < EMB_N; ++c) {
        const float* e = emb + (size_t)c * DIM;
        float a0 = 0.f;
#pragma unroll
        for (int k = 0; k < DIM; ++k) a0 = __builtin_fmaf(fr[k], e[k], a0);
        float d0 = (f2 + e2[c]) - (2.0f * a0);
        if (d0 < best) { best = d0; bidx = c; }
    }
    const float* q = emb + (size_t)bidx * DIM;
    float ps = 0.f;
#pragma unroll
    for (int i = 0; i < DIM; i += 4) {
        float4 qx; qx.x = q[i]; qx.y = q[i+1]; qx.z = q[i+2]; qx.w = q[i+3];
        float dx = qx.x - fr[i], dy = qx.y - fr[i+1], dz = qx.z - fr[i+2], dw = qx.w - fr[i+3];
        ps += dx * dx; ps += dy * dy; ps += dz * dz; ps += dw * dw;
        float4 o;
        o.x = fr[i] + (qx.x - fr[i]); o.y = fr[i+1] + (qx.y - fr[i+1]);
        o.z = fr[i+2] + (qx.z - fr[i+2]); o.w = fr[i+3] + (qx.w - fr[i+3]);
        *(float4*)(out_q + (size_t)v * DIM + i) = o;
    }
    float m = ps * (1.0f / DIM);
    out_idx[v]  = (float)bidx;
    out_loss[v] = m * 0.1f + m * 0.1f;
}

extern "C" void kernel_launch(void* const* d_in, const int* in_sizes, int n_in,
                              void* d_out, int out_size, void* d_ws, size_t ws_size,
                              hipStream_t stream) {
    const float* h   = (const float*)d_in[0];
    const float* emb = (const float*)d_in[1];
    float* out = (float*)d_out;
    float* out_q    = out;                               // 4194304
    float* out_idx  = out + (size_t)NVEC * DIM;          // 131072
    float* out_loss = out + (size_t)NVEC * DIM + NVEC;   // 131072

    // ws layout: e2 4KB | bfrag 64KB
    float*   e2    = (float*)d_ws;
    ushortT* bfrag = (ushortT*)((char*)d_ws + 4096);
    const size_t need = 4096 + (size_t)EMB_N * DIM * sizeof(ushortT);

    if (ws_size >= need) {
        prep_kernel<<<16, 256, 0, stream>>>(emb, e2, bfrag);
        vq_scan<<<1024, 256, 0, stream>>>(h, emb, e2, bfrag,
                                          out_q, out_idx, out_loss);
    } else {
        e2_kernel<<<EMB_N / 256, 256, 0, stream>>>(emb, e2);
        vq_kernel<<<NVEC / 256, 256, 0, stream>>>(h, emb, e2, out_q, out_idx, out_loss);
    }
}

// Round 12
// 126.018 us; speedup vs baseline: 1.1852x; 1.1852x over previous
//
#include <hip/hip_runtime.h>

// VQ-VAE quantizer: h (256,512,32) fp32, embeddings (1024,32) fp32.
// d_out (fp32): quantized_st [4194304] | indices [131072] | loss [131072]
//
// R12: R9's fused certified-filter scan with the b-table SPLIT: 36 KB in LDS
// + 28 KB streamed from global. Diagnosis chain:
//   R8-R10: 64 KB table cyclically streamed through 32 KB L1 -> 0% hit (LRU),
//           every b-load pays L2 latency; extra waves (R10) can't fix that.
//   R11:    full table in LDS -> no misses, but 64 KB -> 2 blocks/CU ->
//           2 waves/SIMD can't hide ds_read+MFMA latency (95us, occ 17%).
//   R12:    36 KB LDS + 28 KB global (28+4KB e2 fits L1 -> high hit rate);
//           lists shrunk (ushort cand, MAXC=8): total LDS 38.5 KB ->
//           4 blocks/CU = 4 waves/SIMD. Same math, same bits, same argmin.
//   prep:  e2 (numpy pairwise) + bf16 B-frag table (MFMA lane layout)
//   scan:  stage LDS half; per wave (32 rows): sweep1 approx min/row (MFMA),
//          T_row = 2^-16*Sum|f_k| + 1e-4; sweep2 recompute (bit-identical),
//          LDS-append qualifiers; tail: overflow rows (P~1e-6) -> cooperative
//          exact scan; owner lane: n==1 -> done, else bit-exact numpy recheck
//          (pairwise ||f||^2, sequential fmaf dot, fl(fl(f2+e2)-2dot),
//          u64 key enc(d)<<32|c = first-occurrence argmin); epilogue.
// History: R3 270 -> R5 193 -> R8 141 -> R9 131 (scan 72) -> R10 132 -> R11 149.

#define EMB_N 1024
#define DIM 32
#define NVEC (256 * 512)
#define NTILES (EMB_N / 16)
#define NT_LDS 36
#define MAXC 8

typedef unsigned long long u64;
typedef unsigned int u32;
typedef unsigned short ushortT;
typedef __attribute__((ext_vector_type(8))) short bf16x8;
typedef __attribute__((ext_vector_type(4))) float f32x4;

__device__ __forceinline__ u32 enc_f32(float x) {
    u32 u = __float_as_uint(x);
    return (u & 0x80000000u) ? ~u : (u | 0x80000000u);  // monotone order-preserving
}
__device__ __forceinline__ ushortT f2bf(float f) {  // RNE fp32->bf16
    u32 u = __float_as_uint(f);
    return (ushortT)((u + 0x7FFFu + ((u >> 16) & 1u)) >> 16);
}
__device__ __forceinline__ u64 shflx_u64(u64 x, int m) {
    int lo = __shfl_xor((int)(u32)x, m);
    int hi = __shfl_xor((int)(x >> 32), m);
    return ((u64)(u32)hi << 32) | (u32)lo;
}

// numpy pairwise ||x||^2, n=32: 8 accumulators stride 8, fixed combine tree
__device__ __forceinline__ float norm2_np(const float* fr) {
    float sq[DIM];
#pragma unroll
    for (int i = 0; i < DIM; ++i) sq[i] = fr[i] * fr[i];
    float r[8];
#pragma unroll
    for (int j = 0; j < 8; ++j)
        r[j] = ((sq[j] + sq[j + 8]) + sq[j + 16]) + sq[j + 24];
    return ((r[0] + r[1]) + (r[2] + r[3])) + ((r[4] + r[5]) + (r[6] + r[7]));
}

// ---- prep: e2 + bf16 B-frag table. frag(nt,lane,j) = bf16(emb[nt*16+(lane&15)][(lane>>4)*8+j])
__global__ __launch_bounds__(256) void prep_kernel(
    const float* __restrict__ emb, float* __restrict__ e2,
    ushortT* __restrict__ bfrag)
{
#pragma clang fp contract(off)
    const int t = blockIdx.x * 256 + threadIdx.x;    // 0..4095
    const int l = t & 63;
    const int row = ((t >> 6) << 4) + (l & 15);
    const int k0 = (l >> 4) * 8;
    const float* ep = emb + (size_t)row * DIM + k0;
    ushortT* dst = bfrag + (size_t)t * 8;
#pragma unroll
    for (int j = 0; j < 8; ++j) dst[j] = f2bf(ep[j]);
    if (t < EMB_N) {
        const float* e = emb + (size_t)t * DIM;
        float tmp[DIM];
#pragma unroll
        for (int i = 0; i < DIM; ++i) tmp[i] = e[i];
        e2[t] = norm2_np(tmp);
    }
}

// sweep bodies as macros so LDS and global segments keep distinct address spaces
#define S1BODY(BEXPR, NT) do {                                                  \
    bf16x8 b = *(const bf16x8*)(BEXPR);                                         \
    f32x4 d0 = __builtin_amdgcn_mfma_f32_16x16x32_bf16(afr0, b, zacc, 0, 0, 0); \
    f32x4 d1 = __builtin_amdgcn_mfma_f32_16x16x32_bf16(afr1, b, zacc, 0, 0, 0); \
    float e2c = e2[(NT) * 16 + col16];                                          \
    _Pragma("unroll")                                                           \
    for (int r = 0; r < 4; ++r) {                                               \
        bs[r]     = fminf(bs[r],     __builtin_fmaf(-2.f, d0[r], e2c));         \
        bs[4 + r] = fminf(bs[4 + r], __builtin_fmaf(-2.f, d1[r], e2c));         \
    }                                                                           \
} while (0)

#define S2BODY(BEXPR, NT) do {                                                  \
    bf16x8 b = *(const bf16x8*)(BEXPR);                                         \
    f32x4 d0 = __builtin_amdgcn_mfma_f32_16x16x32_bf16(afr0, b, zacc, 0, 0, 0); \
    f32x4 d1 = __builtin_amdgcn_mfma_f32_16x16x32_bf16(afr1, b, zacc, 0, 0, 0); \
    float e2c = e2[(NT) * 16 + col16];                                          \
    const u32 cc = (NT) * 16 + col16;                                           \
    bool q[8];                                                                  \
    bool any = false;                                                           \
    _Pragma("unroll")                                                           \
    for (int i = 0; i < 8; ++i) {                                               \
        float s = __builtin_fmaf(-2.f, ((i >> 2) ? d1[i & 3] : d0[i & 3]), e2c);\
        q[i] = (s <= thr[i]);                                                   \
        any |= q[i];                                                            \
    }                                                                           \
    if (__ballot(any)) {                                                        \
        _Pragma("unroll")                                                       \
        for (int i = 0; i < 8; ++i) {                                           \
            if (__ballot(q[i])) {                                               \
                if (q[i]) {                                                     \
                    const int rloc = ((i >> 2) << 4) + quad * 4 + (i & 3);      \
                    u32 slot = atomicAdd(&cnt[rloc], 1u);                       \
                    if (slot < MAXC) cand[rloc * MAXC + slot] = (ushortT)cc;    \
                }                                                               \
            }                                                                   \
        }                                                                       \
    }                                                                           \
} while (0)

// ---- fused scan: split-table, 1 wave = 32 rows, LDS lists, fused tail ----
__global__ __launch_bounds__(256) void vq_scan(
    const float* __restrict__ h,
    const float* __restrict__ emb,
    const float* __restrict__ e2,
    const ushortT* __restrict__ bfrag,
    float* __restrict__ out_q, float* __restrict__ out_idx,
    float* __restrict__ out_loss)
{
#pragma clang fp contract(off)
    __shared__ __align__(16) ushortT s_b[NT_LDS * 512];   // 36 KB
    __shared__ u32     lds_cnt[4][32];                    // 512 B
    __shared__ ushortT lds_cand[4][32 * MAXC];            // 2 KB

    // cooperative stage of the LDS half: 36 KB = 2304 uint4
    {
        const uint4* src = (const uint4*)bfrag;
        uint4* dst = (uint4*)s_b;
        for (int o = threadIdx.x; o < NT_LDS * 64; o += 256) dst[o] = src[o];
    }

    const int wslot = threadIdx.x >> 6;
    const int wid   = (blockIdx.x * 256 + threadIdx.x) >> 6;  // 0..4095
    const int lane  = threadIdx.x & 63;
    const int col16 = lane & 15;
    const int quad  = lane >> 4;
    const size_t row0 = (size_t)wid * 32;

    u32*     cnt  = lds_cnt[wslot];    // wave-private
    ushortT* cand = lds_cand[wslot];
    if (lane < 32) cnt[lane] = 0;

    // A-frags for rows row0+col16 (tile0), row0+16+col16 (tile1); fp32 abs-sums
    bf16x8 afr0, afr1;
    float sa0, sa1;
    {
        const float* ap = h + (row0 + col16) * DIM + quad * 8;
        float4 x = *(const float4*)ap, y = *(const float4*)(ap + 4);
        afr0[0]=(short)f2bf(x.x); afr0[1]=(short)f2bf(x.y); afr0[2]=(short)f2bf(x.z); afr0[3]=(short)f2bf(x.w);
        afr0[4]=(short)f2bf(y.x); afr0[5]=(short)f2bf(y.y); afr0[6]=(short)f2bf(y.z); afr0[7]=(short)f2bf(y.w);
        sa0 = fabsf(x.x)+fabsf(x.y)+fabsf(x.z)+fabsf(x.w)+fabsf(y.x)+fabsf(y.y)+fabsf(y.z)+fabsf(y.w);
        const float* bp = ap + 16 * DIM;
        float4 u = *(const float4*)bp, v = *(const float4*)(bp + 4);
        afr1[0]=(short)f2bf(u.x); afr1[1]=(short)f2bf(u.y); afr1[2]=(short)f2bf(u.z); afr1[3]=(short)f2bf(u.w);
        afr1[4]=(short)f2bf(v.x); afr1[5]=(short)f2bf(v.y); afr1[6]=(short)f2bf(v.z); afr1[7]=(short)f2bf(v.w);
        sa1 = fabsf(u.x)+fabsf(u.y)+fabsf(u.z)+fabsf(u.w)+fabsf(v.x)+fabsf(v.y)+fabsf(v.z)+fabsf(v.w);
    }
    sa0 += __shfl_xor(sa0, 16); sa0 += __shfl_xor(sa0, 32);
    sa1 += __shfl_xor(sa1, 16); sa1 += __shfl_xor(sa1, 32);

    __syncthreads();   // LDS half staged (lists are wave-private; no hazard)

    const f32x4 zacc = {0.f, 0.f, 0.f, 0.f};

    // ---- sweep 1: approx min per slot (slot i: tile i>>2, reg i&3) ----
    float bs[8];
#pragma unroll
    for (int i = 0; i < 8; ++i) bs[i] = 3.4e38f;
#pragma unroll 2
    for (int nt = 0; nt < NT_LDS; ++nt)
        S1BODY(s_b + nt * 512 + lane * 8, nt);
#pragma unroll 2
    for (int nt = NT_LDS; nt < NTILES; ++nt)
        S1BODY(bfrag + nt * 512 + lane * 8, nt);
#pragma unroll
    for (int m = 1; m < 16; m <<= 1)
#pragma unroll
        for (int i = 0; i < 8; ++i) bs[i] = fminf(bs[i], __shfl_xor(bs[i], m));

    // per-row certified threshold: thr = min + 2^-16*Sum|f| + 1e-4
    float thr[8];
#pragma unroll
    for (int i = 0; i < 8; ++i) {
        float sar = __shfl((i >> 2) ? sa1 : sa0, quad * 4 + (i & 3));
        thr[i] = bs[i] + __builtin_fmaf(sar, 0x1p-16f, 1.0e-4f);
    }

    // ---- sweep 2: recompute (bit-identical), LDS-append qualifiers ----
#pragma unroll 2
    for (int nt = 0; nt < NT_LDS; ++nt)
        S2BODY(s_b + nt * 512 + lane * 8, nt);
#pragma unroll 2
    for (int nt = NT_LDS; nt < NTILES; ++nt)
        S2BODY(bfrag + nt * 512 + lane * 8, nt);

    // ---- tail A: overflowed rows (P~1e-6) -> wave-cooperative exact scan ----
    u64 ovf = __ballot((lane < 32) && (cnt[lane & 31] > MAXC));
    while (ovf) {
        const int r = (int)(__ffsll((unsigned long long)ovf) - 1);
        ovf &= ovf - 1;
        const float* fp = h + (row0 + r) * DIM;   // wave-uniform row
        float fu[DIM];
#pragma unroll
        for (int i = 0; i < DIM; i += 4) {
            float4 x = *(const float4*)(fp + i);
            fu[i] = x.x; fu[i + 1] = x.y; fu[i + 2] = x.z; fu[i + 3] = x.w;
        }
        const float f2 = norm2_np(fu);
        u64 bk = ~0ull;
        for (int c = lane; c < EMB_N; c += 64) {
            const float* ep = emb + (size_t)c * DIM;
            float a = 0.f;
#pragma unroll
            for (int k = 0; k < DIM; ++k) a = __builtin_fmaf(fu[k], ep[k], a);
            float dd = (f2 + e2[c]) - (2.0f * a);
            u64 key = ((u64)enc_f32(dd) << 32) | (u32)c;
            if (key < bk) bk = key;
        }
#pragma unroll
        for (int m = 1; m < 64; m <<= 1) {
            u64 o = shflx_u64(bk, m);
            if (o < bk) bk = o;
        }
        if (lane == 0) { cand[r * MAXC] = (ushortT)(bk & 1023u); cnt[r] = 1; }
    }

    // ---- tail B: owner lane per row -> recheck + epilogue ----
    if (lane < 32) {
        const int row = (int)row0 + lane;
        const u32 n = cnt[lane];
        const float* f = h + (size_t)row * DIM;
        float fr[DIM];
#pragma unroll
        for (int i = 0; i < DIM; i += 4) {
            float4 x = *(const float4*)(f + i);
            fr[i] = x.x; fr[i + 1] = x.y; fr[i + 2] = x.z; fr[i + 3] = x.w;
        }
        int bidx;
        if (n == 1) {
            bidx = (int)cand[lane * MAXC];       // sole certified qualifier
        } else {
            const float f2 = norm2_np(fr);
            u64 best = ~0ull;
            for (u32 j = 0; j < n; ++j) {
                const u32 c = (u32)cand[lane * MAXC + j];
                const float* ep = emb + (size_t)c * DIM;
                float a = 0.f;
#pragma unroll
                for (int k = 0; k < DIM; ++k) a = __builtin_fmaf(fr[k], ep[k], a);  // BLAS chain
                float dd = (f2 + e2[c]) - (2.0f * a);     // exact numpy formula
                u64 key = ((u64)enc_f32(dd) << 32) | c;
                if (key < best) best = key;
            }
            bidx = (int)(best & 0xFFFFFFFFu);
        }

        const float* qv = emb + (size_t)bidx * DIM;
        float ps = 0.f;
#pragma unroll
        for (int i = 0; i < DIM; i += 4) {
            float4 qx; qx.x = qv[i]; qx.y = qv[i+1]; qx.z = qv[i+2]; qx.w = qv[i+3];
            float dx = qx.x - fr[i], dy = qx.y - fr[i+1], dz = qx.z - fr[i+2], dw = qx.w - fr[i+3];
            ps += dx * dx; ps += dy * dy; ps += dz * dz; ps += dw * dw;
            float4 o;
            o.x = fr[i]     + (qx.x - fr[i]);
            o.y = fr[i + 1] + (qx.y - fr[i + 1]);
            o.z = fr[i + 2] + (qx.z - fr[i + 2]);
            o.w = fr[i + 3] + (qx.w - fr[i + 3]);
            *(float4*)(out_q + (size_t)row * DIM + i) = o;
        }
        float m = ps * (1.0f / DIM);
        out_idx[row]  = (float)bidx;
        out_loss[row] = m * 0.1f + m * 0.1f;
    }
}

// ---------- fallback (R3-style) if workspace too small ----------
__global__ void e2_kernel(const float* __restrict__ emb, float* __restrict__ e2) {
#pragma clang fp contract(off)
    int c = blockIdx.x * blockDim.x + threadIdx.x;
    if (c >= EMB_N) return;
    const float* e = emb + (size_t)c * DIM;
    float tmp[DIM];
#pragma unroll
    for (int i = 0; i < DIM; ++i) tmp[i] = e[i];
    e2[c] = norm2_np(tmp);
}

__global__ __launch_bounds__(256) void vq_kernel(
    const float* __restrict__ h, const float* __restrict__ emb,
    const float* __restrict__ e2, float* __restrict__ out_q,
    float* __restrict__ out_idx, float* __restrict__ out_loss)
{
#pragma clang fp contract(off)
    const int v = blockIdx.x * blockDim.x + threadIdx.x;
    const float* f = h + (size_t)v * DIM;
    float fr[DIM];
#pragma unroll
    for (int i = 0; i < DIM; i += 4) {
        float4 x = *(const float4*)(f + i);
        fr[i] = x.x; fr[i + 1] = x.y; fr[i + 2] = x.z; fr[i + 3] = x.w;
    }
    const float f2 = norm2_np(fr);
    float best = 3.4e38f; int bidx = 0;
#pragma unroll 1
    for (int c = 0; c < EMB_N; ++c) {
        const float* e = emb + (size_t)c * DIM;
        float a0 = 0.f;
#pragma unroll
        for (int k = 0; k < DIM; ++k) a0 = __builtin_fmaf(fr[k], e[k], a0);
        float d0 = (f2 + e2[c]) - (2.0f * a0);
        if (d0 < best) { best = d0; bidx = c; }
    }
    const float* q = emb + (size_t)bidx * DIM;
    float ps = 0.f;
#pragma unroll
    for (int i = 0; i < DIM; i += 4) {
        float4 qx; qx.x = q[i]; qx.y = q[i+1]; qx.z = q[i+2]; qx.w = q[i+3];
        float dx = qx.x - fr[i], dy = qx.y - fr[i+1], dz = qx.z - fr[i+2], dw = qx.w - fr[i+3];
        ps += dx * dx; ps += dy * dy; ps += dz * dz; ps += dw * dw;
        float4 o;
        o.x = fr[i] + (qx.x - fr[i]); o.y = fr[i+1] + (qx.y - fr[i+1]);
        o.z = fr[i+2] + (qx.z - fr[i+2]); o.w = fr[i+3] + (qx.w - fr[i+3]);
        *(float4*)(out_q + (size_t)v * DIM + i) = o;
    }
    float m = ps * (1.0f / DIM);
    out_idx[v]  = (float)bidx;
    out_loss[v] = m * 0.1f + m * 0.1f;
}

extern "C" void kernel_launch(void* const* d_in, const int* in_sizes, int n_in,
                              void* d_out, int out_size, void* d_ws, size_t ws_size,
                              hipStream_t stream) {
    const float* h   = (const float*)d_in[0];
    const float* emb = (const float*)d_in[1];
    float* out = (float*)d_out;
    float* out_q    = out;                               // 4194304
    float* out_idx  = out + (size_t)NVEC * DIM;          // 131072
    float* out_loss = out + (size_t)NVEC * DIM + NVEC;   // 131072

    // ws layout: e2 4KB | bfrag 64KB
    float*   e2    = (float*)d_ws;
    ushortT* bfrag = (ushortT*)((char*)d_ws + 4096);
    const size_t need = 4096 + (size_t)EMB_N * DIM * sizeof(ushortT);

    if (ws_size >= need) {
        prep_kernel<<<16, 256, 0, stream>>>(emb, e2, bfrag);
        vq_scan<<<1024, 256, 0, stream>>>(h, emb, e2, bfrag,
                                          out_q, out_idx, out_loss);
    } else {
        e2_kernel<<<EMB_N / 256, 256, 0, stream>>>(emb, e2);
        vq_kernel<<<NVEC / 256, 256, 0, stream>>>(h, emb, e2, out_q, out_idx, out_loss);
    }
}